// Round 1
// baseline (1239.424 us; speedup 1.0000x reference)
//
#include <hip/hip_runtime.h>

// ClassicalSelfAttention: out = softmax((X R)(X E)^T / 32) @ X,  X[8192][1024] fp32.
// Strategy:
//  - logits = X (R E^T) X^T / 32. Precompute Mt = E R^T, Y = X Mt^T, L = Y X^T / 32.
//  - All precision-critical GEMMs via f16 hi/lo split (3 MFMA products) -> ~fp32 accuracy.
//  - rowstat: per-row max + 1/sum(exp). PV: on-the-fly exp(L-m) f16 tiles @ Xt (f16, pre-transposed).
// L buffer is chunked by ws_size; early-dead split buffers live at the ws tail and are
// overlapped by L after they die (stream-ordered).

typedef _Float16 f16;
typedef _Float16 f16x4 __attribute__((ext_vector_type(4)));
typedef _Float16 f16x8 __attribute__((ext_vector_type(8)));
typedef float    f32x4 __attribute__((ext_vector_type(4)));
typedef unsigned int u32;

#define N_ROWS 8192
#define D_DIM  1024
#define LOG2E  1.44269504088896340736f

__device__ __forceinline__ void gload_lds16(const void* g, void* l) {
  __builtin_amdgcn_global_load_lds(
      (const __attribute__((address_space(1))) u32*)g,
      (__attribute__((address_space(3))) u32*)l, 16, 0, 0);
}

// Read 8 contiguous f16 along k from row `row` of a [rows][32] f16 tile with
// XOR swizzle byte^=((row&3)<<4). 16-B aligned -> ds_read_b128.
__device__ __forceinline__ f16x8 read_frag(const f16* tile, int row, int lane) {
  int kb = ((lane >> 4) & 3) << 4;
  int phys = row * 64 + (kb ^ ((row & 3) << 4));
  return *(const f16x8*)((const char*)tile + phys);
}

// fp32 -> f16 hi/lo split, vectorized x4
__global__ __launch_bounds__(256) void splitk(const float* __restrict__ in,
                                              f16* __restrict__ hi, f16* __restrict__ lo,
                                              int n4) {
  int i = blockIdx.x * 256 + threadIdx.x;
  if (i >= n4) return;
  float4 v = ((const float4*)in)[i];
  float vv[4] = {v.x, v.y, v.z, v.w};
  f16x4 h, l;
#pragma unroll
  for (int j = 0; j < 4; ++j) {
    f16 hh = (f16)vv[j];
    h[j] = hh;
    l[j] = (f16)(vv[j] - (float)hh);
  }
  *(f16x4*)(hi + (size_t)i * 4) = h;
  *(f16x4*)(lo + (size_t)i * 4) = l;
}

// X[8192][1024] fp32 -> Xt[1024][8192] f16
__global__ __launch_bounds__(256) void transpose_cast(const float* __restrict__ X,
                                                      f16* __restrict__ Xt) {
  __shared__ float tile[32][33];
  int bx = blockIdx.x;          // over D/32
  int by = blockIdx.y;          // over N/32
  int tx = threadIdx.x & 31, ty0 = threadIdx.x >> 5;
#pragma unroll
  for (int r = 0; r < 4; ++r) {
    int ty = ty0 + r * 8;
    tile[ty][tx] = X[(size_t)(by * 32 + ty) * D_DIM + bx * 32 + tx];
  }
  __syncthreads();
#pragma unroll
  for (int r = 0; r < 4; ++r) {
    int ty = ty0 + r * 8;
    Xt[(size_t)(bx * 32 + ty) * N_ROWS + by * 32 + tx] = (f16)tile[tx][ty];
  }
}

// C[M][Ncols] = scale * (Ahi+Alo)[M][1024] * ((Bhi+Blo)[Ncols][1024])^T, split-3 f16 MFMA.
// OUT_SPLIT=1: write Chi/Clo f16 pair instead of fp32 C.
// Tile 128x128, BK=32, 256 threads (4 waves, 2x2 quadrants of 64x64).
template <int OUT_SPLIT>
__global__ __launch_bounds__(256) void gemm_abt(
    const f16* __restrict__ Ahi, const f16* __restrict__ Alo,
    const f16* __restrict__ Bhi, const f16* __restrict__ Blo,
    float scale, int Ncols,
    float* __restrict__ C, f16* __restrict__ Chi, f16* __restrict__ Clo) {
  __shared__ __align__(16) f16 lds[4 * 4096];  // Ahi | Alo | Bhi | Blo, each [128][32]
  const int t = threadIdx.x, w = t >> 6, l = t & 63;
  const int bn = blockIdx.x, bm = blockIdx.y;
  const int wr = (w >> 1) * 64, wc = (w & 1) * 64;
  const char* srcs[4];
  srcs[0] = (const char*)(Ahi + (size_t)bm * 128 * 1024);
  srcs[1] = (const char*)(Alo + (size_t)bm * 128 * 1024);
  srcs[2] = (const char*)(Bhi + (size_t)bn * 128 * 1024);
  srcs[3] = (const char*)(Blo + (size_t)bn * 128 * 1024);
  f32x4 acc[4][4] = {};
  for (int ks = 0; ks < 32; ++ks) {
#pragma unroll
    for (int tt = 0; tt < 4; ++tt)
#pragma unroll
      for (int j = 0; j < 2; ++j) {
        int seg = j * 4 + w;                    // 8 segments of 1024 B per tile
        int p = seg * 1024 + l * 16;            // physical byte in tile (linear dest)
        int r = p >> 6;                         // tile row
        int sw = (p & 63) ^ ((r & 3) << 4);     // inverse-swizzled source byte-in-row
        gload_lds16(srcs[tt] + (size_t)r * 2048 + ks * 64 + sw,
                    (char*)lds + tt * 8192 + seg * 1024);
      }
    __syncthreads();
    f16x8 ah[4], al[4], bh[4], bl[4];
#pragma unroll
    for (int m = 0; m < 4; ++m) {
      int row = wr + m * 16 + (l & 15);
      ah[m] = read_frag(lds, row, l);
      al[m] = read_frag(lds + 4096, row, l);
    }
#pragma unroll
    for (int n = 0; n < 4; ++n) {
      int row = wc + n * 16 + (l & 15);
      bh[n] = read_frag(lds + 8192, row, l);
      bl[n] = read_frag(lds + 12288, row, l);
    }
#pragma unroll
    for (int m = 0; m < 4; ++m)
#pragma unroll
      for (int n = 0; n < 4; ++n) {
        acc[m][n] = __builtin_amdgcn_mfma_f32_16x16x32_f16(ah[m], bh[n], acc[m][n], 0, 0, 0);
        acc[m][n] = __builtin_amdgcn_mfma_f32_16x16x32_f16(ah[m], bl[n], acc[m][n], 0, 0, 0);
        acc[m][n] = __builtin_amdgcn_mfma_f32_16x16x32_f16(al[m], bh[n], acc[m][n], 0, 0, 0);
      }
    __syncthreads();
  }
#pragma unroll
  for (int m = 0; m < 4; ++m)
#pragma unroll
    for (int n = 0; n < 4; ++n)
#pragma unroll
      for (int j = 0; j < 4; ++j) {
        int row = bm * 128 + wr + m * 16 + ((l >> 4) << 2) + j;
        int col = bn * 128 + wc + n * 16 + (l & 15);
        float v = acc[m][n][j] * scale;
        size_t idx = (size_t)row * Ncols + col;
        if (OUT_SPLIT) {
          f16 hh = (f16)v;
          Chi[idx] = hh;
          Clo[idx] = (f16)(v - (float)hh);
        } else {
          C[idx] = v;
        }
      }
}

// Per-row max and 1/sum(exp) over L[row][8192]
__global__ __launch_bounds__(256) void rowstat(const float* __restrict__ L,
                                               float* __restrict__ mrow,
                                               float* __restrict__ sinv) {
  const int row = blockIdx.x, t = threadIdx.x, w = t >> 6, l = t & 63;
  const float4* p = (const float4*)(L + (size_t)row * N_ROWS);
  __shared__ float red[8];
  float mx = -3.4e38f;
#pragma unroll
  for (int i = 0; i < 8; ++i) {
    float4 v = p[t + i * 256];
    mx = fmaxf(mx, fmaxf(fmaxf(v.x, v.y), fmaxf(v.z, v.w)));
  }
#pragma unroll
  for (int off = 32; off; off >>= 1) mx = fmaxf(mx, __shfl_xor(mx, off));
  if (l == 0) red[w] = mx;
  __syncthreads();
  mx = fmaxf(fmaxf(red[0], red[1]), fmaxf(red[2], red[3]));
  float s = 0.f;
#pragma unroll
  for (int i = 0; i < 8; ++i) {
    float4 v = p[t + i * 256];
    s += exp2f((v.x - mx) * LOG2E) + exp2f((v.y - mx) * LOG2E) +
         exp2f((v.z - mx) * LOG2E) + exp2f((v.w - mx) * LOG2E);
  }
#pragma unroll
  for (int off = 32; off; off >>= 1) s += __shfl_xor(s, off);
  if (l == 0) red[4 + w] = s;
  __syncthreads();
  if (t == 0) {
    mrow[row] = mx;
    sinv[row] = 1.0f / (red[4] + red[5] + red[6] + red[7]);
  }
}

// out[row][col] = (1/s_row) * sum_j exp(L[row][j]-m_row) * Xt[col][j]
// Tile 128x256, BK=32, 512 threads (8 waves, 2x4 quadrants of 64x64).
__global__ __launch_bounds__(512) void pv_gemm(
    const float* __restrict__ L, const float* __restrict__ mrow,
    const float* __restrict__ sinv, const f16* __restrict__ Xt,
    float* __restrict__ out) {
  __shared__ __align__(16) f16 ldsP[128 * 32];  // 8 KB
  __shared__ __align__(16) f16 ldsB[256 * 32];  // 16 KB
  const int t = threadIdx.x, w = t >> 6, l = t & 63;
  const int bn = blockIdx.x, bm = blockIdx.y;
  const int wr = (w >> 2) * 64, wc = (w & 3) * 64;
  const int pr = t >> 3, pc = t & 7;            // P staging: 64 rows x 8 float4
  const float m0 = mrow[bm * 128 + pr];
  const float m1 = mrow[bm * 128 + pr + 64];
  const float* Lr0 = L + (size_t)(bm * 128 + pr) * N_ROWS + pc * 4;
  const float* Lr1 = L + (size_t)(bm * 128 + pr + 64) * N_ROWS + pc * 4;
  const int phys0 = pr * 64 + ((pc * 8) ^ ((pr & 3) << 4));
  const int phys1 = (pr + 64) * 64 + ((pc * 8) ^ ((pr & 3) << 4));
  f32x4 acc[4][4] = {};
  for (int ks = 0; ks < 256; ++ks) {
#pragma unroll
    for (int j = 0; j < 2; ++j) {
      int seg = j * 8 + w;                      // 16 segments of 1024 B
      int p = seg * 1024 + l * 16;
      int r = p >> 6;
      int sw = (p & 63) ^ ((r & 3) << 4);
      gload_lds16((const char*)(Xt + (size_t)(bn * 256 + r) * N_ROWS) + ks * 64 + sw,
                  (char*)ldsB + seg * 1024);
    }
    {
      float4 v0 = *(const float4*)(Lr0 + (size_t)ks * 32);
      float4 v1 = *(const float4*)(Lr1 + (size_t)ks * 32);
      f16x4 e0, e1;
      e0[0] = (f16)exp2f((v0.x - m0) * LOG2E);
      e0[1] = (f16)exp2f((v0.y - m0) * LOG2E);
      e0[2] = (f16)exp2f((v0.z - m0) * LOG2E);
      e0[3] = (f16)exp2f((v0.w - m0) * LOG2E);
      e1[0] = (f16)exp2f((v1.x - m1) * LOG2E);
      e1[1] = (f16)exp2f((v1.y - m1) * LOG2E);
      e1[2] = (f16)exp2f((v1.z - m1) * LOG2E);
      e1[3] = (f16)exp2f((v1.w - m1) * LOG2E);
      *(f16x4*)((char*)ldsP + phys0) = e0;
      *(f16x4*)((char*)ldsP + phys1) = e1;
    }
    __syncthreads();
    f16x8 pa[4], xb[4];
#pragma unroll
    for (int m = 0; m < 4; ++m) pa[m] = read_frag(ldsP, wr + m * 16 + (l & 15), l);
#pragma unroll
    for (int n = 0; n < 4; ++n) xb[n] = read_frag(ldsB, wc + n * 16 + (l & 15), l);
#pragma unroll
    for (int m = 0; m < 4; ++m)
#pragma unroll
      for (int n = 0; n < 4; ++n)
        acc[m][n] = __builtin_amdgcn_mfma_f32_16x16x32_f16(pa[m], xb[n], acc[m][n], 0, 0, 0);
    __syncthreads();
  }
#pragma unroll
  for (int m = 0; m < 4; ++m)
#pragma unroll
    for (int n = 0; n < 4; ++n)
#pragma unroll
      for (int j = 0; j < 4; ++j) {
        int row = bm * 128 + wr + m * 16 + ((l >> 4) << 2) + j;
        int col = bn * 256 + wc + n * 16 + (l & 15);
        out[(size_t)row * D_DIM + col] = acc[m][n][j] * sinv[row];
      }
}

extern "C" void kernel_launch(void* const* d_in, const int* in_sizes, int n_in,
                              void* d_out, int out_size, void* d_ws, size_t ws_size,
                              hipStream_t stream) {
  const float* X = (const float*)d_in[0];
  const float* R = (const float*)d_in[1];
  const float* E = (const float*)d_in[2];
  float* out = (float*)d_out;

  // Front allocations (live through the whole chunk loop)
  char* p = (char*)d_ws;
  auto alloc = [&](size_t bytes) -> char* {
    char* r = p;
    p += (bytes + 255) & ~(size_t)255;
    return r;
  };
  f16* Xhi = (f16*)alloc((size_t)N_ROWS * D_DIM * 2);
  f16* Xlo = (f16*)alloc((size_t)N_ROWS * D_DIM * 2);
  f16* Yhi = (f16*)alloc((size_t)N_ROWS * D_DIM * 2);
  f16* Ylo = (f16*)alloc((size_t)N_ROWS * D_DIM * 2);
  f16* Xt  = (f16*)alloc((size_t)N_ROWS * D_DIM * 2);
  float* mrow = (float*)alloc((size_t)N_ROWS * 4);
  float* sinv = (float*)alloc((size_t)N_ROWS * 4);
  float* Lbuf = (float*)p;
  size_t front = (size_t)(p - (char*)d_ws);

  // Tail allocations (dead after the Y GEMM; L may overlap them afterwards)
  char* tail = (char*)d_ws + ws_size;
  auto alloct = [&](size_t bytes) -> char* {
    tail = (char*)(((uintptr_t)tail - bytes) & ~(uintptr_t)255);
    return tail;
  };
  f16* Rhi  = (f16*)alloct((size_t)D_DIM * D_DIM * 2);
  f16* Rlo  = (f16*)alloct((size_t)D_DIM * D_DIM * 2);
  f16* Ehi  = (f16*)alloct((size_t)D_DIM * D_DIM * 2);
  f16* Elo  = (f16*)alloct((size_t)D_DIM * D_DIM * 2);
  f16* Mthi = (f16*)alloct((size_t)D_DIM * D_DIM * 2);
  f16* Mtlo = (f16*)alloct((size_t)D_DIM * D_DIM * 2);

  size_t avail = ws_size > front ? ws_size - front : 0;
  int CH = (int)(avail / ((size_t)N_ROWS * 4));
  if (CH > N_ROWS) CH = N_ROWS;
  CH &= ~127;
  if (CH < 128) CH = 128;  // below this ws is insufficient; nothing better to do

  // 1. splits + transpose
  splitk<<<dim3((N_ROWS * D_DIM / 4 + 255) / 256), 256, 0, stream>>>(X, Xhi, Xlo, N_ROWS * D_DIM / 4);
  splitk<<<dim3((D_DIM * D_DIM / 4 + 255) / 256), 256, 0, stream>>>(R, Rhi, Rlo, D_DIM * D_DIM / 4);
  splitk<<<dim3((D_DIM * D_DIM / 4 + 255) / 256), 256, 0, stream>>>(E, Ehi, Elo, D_DIM * D_DIM / 4);
  transpose_cast<<<dim3(D_DIM / 32, N_ROWS / 32), 256, 0, stream>>>(X, Xt);

  // 2. Mt = E R^T  (so Mt^T = R E^T = M), split output
  gemm_abt<1><<<dim3(8, 8), 256, 0, stream>>>(Ehi, Elo, Rhi, Rlo, 1.0f, D_DIM,
                                              nullptr, Mthi, Mtlo);
  // 3. Y = X Mt^T = X M, split output
  gemm_abt<1><<<dim3(8, 64), 256, 0, stream>>>(Xhi, Xlo, Mthi, Mtlo, 1.0f, D_DIM,
                                               nullptr, Yhi, Ylo);

  // 4. chunked: L = Y X^T / 32 ; rowstat ; out = softmax(L) @ X
  for (int c0 = 0; c0 < N_ROWS; c0 += CH) {
    int rows = (N_ROWS - c0 < CH) ? (N_ROWS - c0) : CH;
    gemm_abt<0><<<dim3(N_ROWS / 128, rows / 128), 256, 0, stream>>>(
        Yhi + (size_t)c0 * D_DIM, Ylo + (size_t)c0 * D_DIM, Xhi, Xlo,
        0.03125f, N_ROWS, Lbuf, nullptr, nullptr);
    rowstat<<<dim3(rows), 256, 0, stream>>>(Lbuf, mrow, sinv);
    pv_gemm<<<dim3(D_DIM / 256, rows / 128), 512, 0, stream>>>(
        Lbuf, mrow, sinv, Xt, out + (size_t)c0 * D_DIM);
  }
}

// Round 2
// 862.470 us; speedup vs baseline: 1.4371x; 1.4371x over previous
//
#include <hip/hip_runtime.h>

// ClassicalSelfAttention: out = softmax((X R)(X E)^T / 32) @ X,  X[8192][1024] fp32.
//  - logits = X (R E^T) X^T / 32. Precompute Mt = E R^T, Y = X Mt^T, L = Y X^T / 32.
//  - Precision-critical GEMMs via f16 hi/lo split (3 MFMA products) -> ~fp32 accuracy.
//  - pexp: per-row softmax of L -> f16 P written IN-PLACE over L (row stride 16384 f16).
//  - gemm_pv: plain f16 GEMM out = P @ Xt^T, 64x128 tile, BK=64.
// L buffer is chunked by ws_size; early-dead split buffers live at the ws tail.

typedef _Float16 f16;
typedef _Float16 f16x4 __attribute__((ext_vector_type(4)));
typedef _Float16 f16x8 __attribute__((ext_vector_type(8)));
typedef float    f32x4 __attribute__((ext_vector_type(4)));
typedef unsigned int u32;

#define N_ROWS 8192
#define D_DIM  1024
#define LOG2E  1.44269504088896340736f

__device__ __forceinline__ void gload_lds16(const void* g, void* l) {
  __builtin_amdgcn_global_load_lds(
      (const __attribute__((address_space(1))) u32*)g,
      (__attribute__((address_space(3))) u32*)l, 16, 0, 0);
}

// ---- BK=32 tiles (64 B rows), swizzle byte^=((row&3)<<4) ----
__device__ __forceinline__ f16x8 read_frag(const f16* tile, int row, int lane) {
  int kb = ((lane >> 4) & 3) << 4;
  int phys = row * 64 + (kb ^ ((row & 3) << 4));
  return *(const f16x8*)((const char*)tile + phys);
}

// ---- BK=64 tiles (128 B rows), swizzle byte^=((row&7)<<4) ----
__device__ __forceinline__ f16x8 read_frag64(const f16* tile, int row, int lane, int ks2) {
  int kb = ks2 * 64 + (((lane >> 4) & 3) << 4);
  int phys = row * 128 + (kb ^ ((row & 7) << 4));
  return *(const f16x8*)((const char*)tile + phys);
}

// fp32 -> f16 hi/lo split, vectorized x4
__global__ __launch_bounds__(256) void splitk(const float* __restrict__ in,
                                              f16* __restrict__ hi, f16* __restrict__ lo,
                                              int n4) {
  int i = blockIdx.x * 256 + threadIdx.x;
  if (i >= n4) return;
  float4 v = ((const float4*)in)[i];
  float vv[4] = {v.x, v.y, v.z, v.w};
  f16x4 h, l;
#pragma unroll
  for (int j = 0; j < 4; ++j) {
    f16 hh = (f16)vv[j];
    h[j] = hh;
    l[j] = (f16)(vv[j] - (float)hh);
  }
  *(f16x4*)(hi + (size_t)i * 4) = h;
  *(f16x4*)(lo + (size_t)i * 4) = l;
}

// X[8192][1024] fp32 -> Xt[1024][8192] f16
__global__ __launch_bounds__(256) void transpose_cast(const float* __restrict__ X,
                                                      f16* __restrict__ Xt) {
  __shared__ float tile[32][33];
  int bx = blockIdx.x, by = blockIdx.y;
  int tx = threadIdx.x & 31, ty0 = threadIdx.x >> 5;
#pragma unroll
  for (int r = 0; r < 4; ++r) {
    int ty = ty0 + r * 8;
    tile[ty][tx] = X[(size_t)(by * 32 + ty) * D_DIM + bx * 32 + tx];
  }
  __syncthreads();
#pragma unroll
  for (int r = 0; r < 4; ++r) {
    int ty = ty0 + r * 8;
    Xt[(size_t)(bx * 32 + ty) * N_ROWS + by * 32 + tx] = (f16)tile[tx][ty];
  }
}

// C[M][Ncols] = scale * (Ahi+Alo)[M][1024] * ((Bhi+Blo)[Ncols][1024])^T, split-3 f16 MFMA.
// Tile 128x128, BK=32, 256 threads (4 waves, 2x2 quadrants of 64x64).
template <int OUT_SPLIT>
__global__ __launch_bounds__(256) void gemm_abt(
    const f16* __restrict__ Ahi, const f16* __restrict__ Alo,
    const f16* __restrict__ Bhi, const f16* __restrict__ Blo,
    float scale, int Ncols,
    float* __restrict__ C, f16* __restrict__ Chi, f16* __restrict__ Clo) {
  __shared__ __align__(16) f16 lds[4 * 4096];  // Ahi | Alo | Bhi | Blo, each [128][32]
  const int t = threadIdx.x, w = t >> 6, l = t & 63;
  const int bn = blockIdx.x, bm = blockIdx.y;
  const int wr = (w >> 1) * 64, wc = (w & 1) * 64;
  const char* srcs[4];
  srcs[0] = (const char*)(Ahi + (size_t)bm * 128 * 1024);
  srcs[1] = (const char*)(Alo + (size_t)bm * 128 * 1024);
  srcs[2] = (const char*)(Bhi + (size_t)bn * 128 * 1024);
  srcs[3] = (const char*)(Blo + (size_t)bn * 128 * 1024);
  f32x4 acc[4][4] = {};
  for (int ks = 0; ks < 32; ++ks) {
#pragma unroll
    for (int tt = 0; tt < 4; ++tt)
#pragma unroll
      for (int j = 0; j < 2; ++j) {
        int seg = j * 4 + w;
        int p = seg * 1024 + l * 16;
        int r = p >> 6;
        int sw = (p & 63) ^ ((r & 3) << 4);
        gload_lds16(srcs[tt] + (size_t)r * 2048 + ks * 64 + sw,
                    (char*)lds + tt * 8192 + seg * 1024);
      }
    __syncthreads();
    f16x8 ah[4], al[4], bh[4], bl[4];
#pragma unroll
    for (int m = 0; m < 4; ++m) {
      int row = wr + m * 16 + (l & 15);
      ah[m] = read_frag(lds, row, l);
      al[m] = read_frag(lds + 4096, row, l);
    }
#pragma unroll
    for (int n = 0; n < 4; ++n) {
      int row = wc + n * 16 + (l & 15);
      bh[n] = read_frag(lds + 8192, row, l);
      bl[n] = read_frag(lds + 12288, row, l);
    }
#pragma unroll
    for (int m = 0; m < 4; ++m)
#pragma unroll
      for (int n = 0; n < 4; ++n) {
        acc[m][n] = __builtin_amdgcn_mfma_f32_16x16x32_f16(ah[m], bh[n], acc[m][n], 0, 0, 0);
        acc[m][n] = __builtin_amdgcn_mfma_f32_16x16x32_f16(ah[m], bl[n], acc[m][n], 0, 0, 0);
        acc[m][n] = __builtin_amdgcn_mfma_f32_16x16x32_f16(al[m], bh[n], acc[m][n], 0, 0, 0);
      }
    __syncthreads();
  }
#pragma unroll
  for (int m = 0; m < 4; ++m)
#pragma unroll
    for (int n = 0; n < 4; ++n)
#pragma unroll
      for (int j = 0; j < 4; ++j) {
        int row = bm * 128 + wr + m * 16 + ((l >> 4) << 2) + j;
        int col = bn * 128 + wc + n * 16 + (l & 15);
        float v = acc[m][n][j] * scale;
        size_t idx = (size_t)row * Ncols + col;
        if (OUT_SPLIT) {
          f16 hh = (f16)v;
          Chi[idx] = hh;
          Clo[idx] = (f16)(v - (float)hh);
        } else {
          C[idx] = v;
        }
      }
}

// Row softmax: read L row (8192 f32) into registers, reduce max & sum(exp),
// write P = exp(L-m)/S as f16 IN-PLACE over the first half of the row.
// P row stride = 16384 f16 elements (= 32 KB = one L row).
__global__ __launch_bounds__(256) void pexp(const float* __restrict__ L,
                                            f16* __restrict__ P) {
  const int row = blockIdx.x, t = threadIdx.x, w = t >> 6, l = t & 63;
  const float4* p = (const float4*)(L + (size_t)row * N_ROWS);
  __shared__ float red[8];
  float4 v[8];
#pragma unroll
  for (int i = 0; i < 8; ++i) v[i] = p[t + i * 256];
  float mx = -3.4e38f;
#pragma unroll
  for (int i = 0; i < 8; ++i)
    mx = fmaxf(mx, fmaxf(fmaxf(v[i].x, v[i].y), fmaxf(v[i].z, v[i].w)));
#pragma unroll
  for (int off = 32; off; off >>= 1) mx = fmaxf(mx, __shfl_xor(mx, off));
  if (l == 0) red[w] = mx;
  __syncthreads();
  mx = fmaxf(fmaxf(red[0], red[1]), fmaxf(red[2], red[3]));
  float e[8][4];
  float s = 0.f;
#pragma unroll
  for (int i = 0; i < 8; ++i) {
    e[i][0] = exp2f((v[i].x - mx) * LOG2E);
    e[i][1] = exp2f((v[i].y - mx) * LOG2E);
    e[i][2] = exp2f((v[i].z - mx) * LOG2E);
    e[i][3] = exp2f((v[i].w - mx) * LOG2E);
    s += (e[i][0] + e[i][1]) + (e[i][2] + e[i][3]);
  }
#pragma unroll
  for (int off = 32; off; off >>= 1) s += __shfl_xor(s, off);
  if (l == 0) red[4 + w] = s;
  __syncthreads();  // also guarantees ALL loads above finished before any write below
  float sinv = 1.0f / (red[4] + red[5] + red[6] + red[7]);
  f16* prow = P + (size_t)row * 16384;
#pragma unroll
  for (int i = 0; i < 8; ++i) {
    f16x4 h;
    h[0] = (f16)(e[i][0] * sinv);
    h[1] = (f16)(e[i][1] * sinv);
    h[2] = (f16)(e[i][2] * sinv);
    h[3] = (f16)(e[i][3] * sinv);
    *(f16x4*)(prow + (size_t)(t + i * 256) * 4) = h;
  }
}

// out[M][1024] = P[M][8192] @ (Xt[1024][8192])^T, plain f16 MFMA.
// Tile 64(M)x128(N), BK=64, 256 threads (4 waves, 2x2 of 32x64).
__global__ __launch_bounds__(256) void gemm_pv(
    const f16* __restrict__ P,   // row stride 16384
    const f16* __restrict__ Xt,  // row stride 8192
    float* __restrict__ out) {
  __shared__ __align__(16) f16 ldsA[64 * 64];    // 8 KB, rows 128 B
  __shared__ __align__(16) f16 ldsB[128 * 64];   // 16 KB
  const int t = threadIdx.x, w = t >> 6, l = t & 63;
  const int bn = blockIdx.x, bm = blockIdx.y;
  const int wr = (w >> 1) * 32, wc = (w & 1) * 64;
  const char* Abase = (const char*)(P + (size_t)bm * 64 * 16384);
  const char* Bbase = (const char*)(Xt + (size_t)bn * 128 * 8192);
  f32x4 acc[2][4] = {};
  for (int ks = 0; ks < 128; ++ks) {
#pragma unroll
    for (int s = 0; s < 2; ++s) {
      int p = s * 4096 + t * 16;
      int r = p >> 7, q = p & 127;
      int sq = q ^ ((r & 7) << 4);
      gload_lds16(Abase + (size_t)r * 32768 + ks * 128 + sq, (char*)ldsA + p);
    }
#pragma unroll
    for (int s = 0; s < 4; ++s) {
      int p = s * 4096 + t * 16;
      int r = p >> 7, q = p & 127;
      int sq = q ^ ((r & 7) << 4);
      gload_lds16(Bbase + (size_t)r * 16384 + ks * 128 + sq, (char*)ldsB + p);
    }
    __syncthreads();
#pragma unroll
    for (int ks2 = 0; ks2 < 2; ++ks2) {
      f16x8 a[2], b[4];
#pragma unroll
      for (int m = 0; m < 2; ++m) a[m] = read_frag64(ldsA, wr + m * 16 + (l & 15), l, ks2);
#pragma unroll
      for (int n = 0; n < 4; ++n) b[n] = read_frag64(ldsB, wc + n * 16 + (l & 15), l, ks2);
#pragma unroll
      for (int m = 0; m < 2; ++m)
#pragma unroll
        for (int n = 0; n < 4; ++n)
          acc[m][n] = __builtin_amdgcn_mfma_f32_16x16x32_f16(a[m], b[n], acc[m][n], 0, 0, 0);
    }
    __syncthreads();
  }
#pragma unroll
  for (int m = 0; m < 2; ++m)
#pragma unroll
    for (int n = 0; n < 4; ++n)
#pragma unroll
      for (int j = 0; j < 4; ++j) {
        int row = bm * 64 + wr + m * 16 + ((l >> 4) << 2) + j;
        int col = bn * 128 + wc + n * 16 + (l & 15);
        out[(size_t)row * D_DIM + col] = acc[m][n][j];
      }
}

extern "C" void kernel_launch(void* const* d_in, const int* in_sizes, int n_in,
                              void* d_out, int out_size, void* d_ws, size_t ws_size,
                              hipStream_t stream) {
  const float* X = (const float*)d_in[0];
  const float* R = (const float*)d_in[1];
  const float* E = (const float*)d_in[2];
  float* out = (float*)d_out;

  char* p = (char*)d_ws;
  auto alloc = [&](size_t bytes) -> char* {
    char* r = p;
    p += (bytes + 255) & ~(size_t)255;
    return r;
  };
  f16* Xhi = (f16*)alloc((size_t)N_ROWS * D_DIM * 2);
  f16* Xlo = (f16*)alloc((size_t)N_ROWS * D_DIM * 2);
  f16* Yhi = (f16*)alloc((size_t)N_ROWS * D_DIM * 2);
  f16* Ylo = (f16*)alloc((size_t)N_ROWS * D_DIM * 2);
  f16* Xt  = (f16*)alloc((size_t)N_ROWS * D_DIM * 2);
  float* Lbuf = (float*)p;
  size_t front = (size_t)(p - (char*)d_ws);

  char* tail = (char*)d_ws + ws_size;
  auto alloct = [&](size_t bytes) -> char* {
    tail = (char*)(((uintptr_t)tail - bytes) & ~(uintptr_t)255);
    return tail;
  };
  f16* Rhi  = (f16*)alloct((size_t)D_DIM * D_DIM * 2);
  f16* Rlo  = (f16*)alloct((size_t)D_DIM * D_DIM * 2);
  f16* Ehi  = (f16*)alloct((size_t)D_DIM * D_DIM * 2);
  f16* Elo  = (f16*)alloct((size_t)D_DIM * D_DIM * 2);
  f16* Mthi = (f16*)alloct((size_t)D_DIM * D_DIM * 2);
  f16* Mtlo = (f16*)alloct((size_t)D_DIM * D_DIM * 2);

  size_t avail = ws_size > front ? ws_size - front : 0;
  int CH = (int)(avail / ((size_t)N_ROWS * 4));
  if (CH > N_ROWS) CH = N_ROWS;
  CH &= ~127;
  if (CH < 128) CH = 128;

  // 1. splits + transpose
  splitk<<<dim3((N_ROWS * D_DIM / 4 + 255) / 256), 256, 0, stream>>>(X, Xhi, Xlo, N_ROWS * D_DIM / 4);
  splitk<<<dim3((D_DIM * D_DIM / 4 + 255) / 256), 256, 0, stream>>>(R, Rhi, Rlo, D_DIM * D_DIM / 4);
  splitk<<<dim3((D_DIM * D_DIM / 4 + 255) / 256), 256, 0, stream>>>(E, Ehi, Elo, D_DIM * D_DIM / 4);
  transpose_cast<<<dim3(D_DIM / 32, N_ROWS / 32), 256, 0, stream>>>(X, Xt);

  // 2. Mt = E R^T  (so Mt^T = R E^T = M)
  gemm_abt<1><<<dim3(8, 8), 256, 0, stream>>>(Ehi, Elo, Rhi, Rlo, 1.0f, D_DIM,
                                              nullptr, Mthi, Mtlo);
  // 3. Y = X Mt^T = X M
  gemm_abt<1><<<dim3(8, 64), 256, 0, stream>>>(Xhi, Xlo, Mthi, Mtlo, 1.0f, D_DIM,
                                               nullptr, Yhi, Ylo);

  // 4. chunked: L = Y X^T / 32 ; pexp (in-place P) ; out = P @ Xt^T
  for (int c0 = 0; c0 < N_ROWS; c0 += CH) {
    int rows = (N_ROWS - c0 < CH) ? (N_ROWS - c0) : CH;
    gemm_abt<0><<<dim3(N_ROWS / 128, rows / 128), 256, 0, stream>>>(
        Yhi + (size_t)c0 * D_DIM, Ylo + (size_t)c0 * D_DIM, Xhi, Xlo,
        0.03125f, N_ROWS, Lbuf, nullptr, nullptr);
    pexp<<<dim3(rows), 256, 0, stream>>>(Lbuf, (f16*)Lbuf);
    gemm_pv<<<dim3(D_DIM / 128, rows / 64), 256, 0, stream>>>(
        (const f16*)Lbuf, Xt, out + (size_t)c0 * D_DIM);
  }
}